// Round 7
// baseline (264.680 us; speedup 1.0000x reference)
//
#include <hip/hip_runtime.h>
#include <hip/hip_bf16.h>
#include <stdint.h>

// B=4, C=512, H=W=64 -> N=4096. Channel-first x [B,C,N].
#define C_DIM 512
#define N_DIM 4096
#define B_DIM 4

typedef __bf16 bf16x8 __attribute__((ext_vector_type(8)));
typedef float f32x4 __attribute__((ext_vector_type(4)));

static __device__ __forceinline__ unsigned short f2bf(float x) {
  unsigned u = __float_as_uint(x);
  unsigned r = (u + 0x7fffu + ((u >> 16) & 1u)) >> 16;
  return (unsigned short)r;
}

// convert weights to bf16; transpose wq,wk,wv (z=0,1,2), straight-copy wp (z=3)
__global__ __launch_bounds__(256) void cvtT_weights(
    const float* __restrict__ wq, const float* __restrict__ wk,
    const float* __restrict__ wv, const float* __restrict__ wp,
    unsigned short* __restrict__ oq, unsigned short* __restrict__ ok,
    unsigned short* __restrict__ ov, unsigned short* __restrict__ op) {
  __shared__ float t[32][33];
  const int zz = blockIdx.z;
  const float* w = zz == 0 ? wq : zz == 1 ? wk : zz == 2 ? wv : wp;
  unsigned short* o = zz == 0 ? oq : zz == 1 ? ok : zz == 2 ? ov : op;
  const int r0 = blockIdx.y * 32, c0 = blockIdx.x * 32;
  const int tx = threadIdx.x, ty = threadIdx.y;
  if (zz < 3) {
    #pragma unroll
    for (int i = ty; i < 32; i += 8) t[i][tx] = w[(r0 + i) * C_DIM + c0 + tx];
    __syncthreads();
    #pragma unroll
    for (int i = ty; i < 32; i += 8)
      o[(size_t)(c0 + i) * C_DIM + r0 + tx] = f2bf(t[tx][i]);
  } else {
    #pragma unroll
    for (int i = ty; i < 32; i += 8)
      o[(size_t)(r0 + i) * C_DIM + c0 + tx] = f2bf(w[(r0 + i) * C_DIM + c0 + tx]);
  }
}

// u[c] = sum_o wk[o,c]*bq[o]  (block 0);  bvp[o] = sum_m wp[o,m]*bv[m] (block 1)
__global__ __launch_bounds__(512) void vec_prep(
    const float* __restrict__ wk, const float* __restrict__ bq,
    const float* __restrict__ wp, const float* __restrict__ bv,
    float* __restrict__ u, float* __restrict__ bvp) {
  const int t = threadIdx.x;
  if (blockIdx.x == 0) {
    float s = 0.f;
    for (int o = 0; o < C_DIM; ++o) s += wk[(size_t)o * C_DIM + t] * bq[o];
    u[t] = s;
  } else {
    float s = 0.f;
    for (int m = 0; m < C_DIM; ++m) s += wp[(size_t)t * C_DIM + m] * bv[m];
    bvp[t] = s;
  }
}

// x [B,C,N] f32 -> Xt [B,N,C] bf16
__global__ __launch_bounds__(256) void transpose_x(
    const float* __restrict__ x, unsigned short* __restrict__ Xt) {
  __shared__ float t[32][33];
  const int b = blockIdx.z;
  const float* xb = x + (size_t)b * C_DIM * N_DIM;
  unsigned short* xtb = Xt + (size_t)b * N_DIM * C_DIM;
  const int n0 = blockIdx.x * 32, c0 = blockIdx.y * 32;
  const int tx = threadIdx.x, ty = threadIdx.y;
  #pragma unroll
  for (int i = ty; i < 32; i += 8)
    t[i][tx] = xb[(size_t)(c0 + i) * N_DIM + n0 + tx];
  __syncthreads();
  #pragma unroll
  for (int i = ty; i < 32; i += 8)
    xtb[(size_t)(n0 + i) * C_DIM + c0 + tx] = f2bf(t[tx][i]);
}

// T[row] = rs * sum_c Xt[row,c]*u[c]   (wave per row, 4 rows/block)
__global__ __launch_bounds__(256) void rowdot_T(
    const unsigned short* __restrict__ Xt, const float* __restrict__ u,
    float* __restrict__ T) {
  const int row = blockIdx.x * 4 + (threadIdx.x >> 6);
  const int lane = threadIdx.x & 63;
  uint4 v = *reinterpret_cast<const uint4*>(Xt + (size_t)row * C_DIM + lane * 8);
  unsigned ua[4] = {v.x, v.y, v.z, v.w};
  const float* up = u + lane * 8;
  float s = 0.f;
  #pragma unroll
  for (int i = 0; i < 4; ++i) {
    s += __uint_as_float(ua[i] << 16) * up[2 * i];
    s += __uint_as_float(ua[i] & 0xffff0000u) * up[2 * i + 1];
  }
  #pragma unroll
  for (int off = 32; off >= 1; off >>= 1) s += __shfl_xor(s, off);
  if (lane == 0) T[row] = 0.044194173824159216f * s;
}

// ---------------- 128^2-tile 2-phase NT GEMM (small/mid GEMMs) -------------
// C[i,j] = sum_k A[i,k]B[j,k]; BIAS: 0 none, 2 +bias[row]. bf16 out.
template<int BIAS>
__global__ __launch_bounds__(256, 2) void gemm_nt(
    const unsigned short* __restrict__ A, long sA,
    const unsigned short* __restrict__ B, long sB,
    unsigned short* __restrict__ Cp, long sC,
    int K, int ldc, const float* __restrict__ bias) {
  const int z = blockIdx.z;
  A += (size_t)z * sA;
  B += (size_t)z * sB;
  const int tid = threadIdx.x;
  const int wid = tid >> 6, lane = tid & 63;
  __shared__ unsigned short As[128 * 32];
  __shared__ unsigned short Bs[128 * 32];
  const int wm = (wid >> 1) * 64, wn = (wid & 1) * 64;
  f32x4 acc[4][4] = {};
  const size_t rowA0 = (size_t)blockIdx.x * 128;
  const size_t rowB0 = (size_t)blockIdx.y * 128;
  const int sgrp = wid * 2;
  const int r0 = (sgrp * 64 + lane) >> 2;
  const int r1 = ((sgrp + 1) * 64 + lane) >> 2;
  const int cc = ((lane & 3) ^ ((lane >> 3) & 3)) * 8;
  const int lr = lane & 15;
  const int koff = (((lane >> 4) ^ ((lr >> 1) & 3))) * 8;

  for (int k0 = 0; k0 < K; k0 += 32) {
    __syncthreads();
    __builtin_amdgcn_global_load_lds(
        (const __attribute__((address_space(1))) void*)(A + (rowA0 + r0) * K + k0 + cc),
        (__attribute__((address_space(3))) void*)(As + sgrp * 512), 16, 0, 0);
    __builtin_amdgcn_global_load_lds(
        (const __attribute__((address_space(1))) void*)(A + (rowA0 + r1) * K + k0 + cc),
        (__attribute__((address_space(3))) void*)(As + (sgrp + 1) * 512), 16, 0, 0);
    __builtin_amdgcn_global_load_lds(
        (const __attribute__((address_space(1))) void*)(B + (rowB0 + r0) * K + k0 + cc),
        (__attribute__((address_space(3))) void*)(Bs + sgrp * 512), 16, 0, 0);
    __builtin_amdgcn_global_load_lds(
        (const __attribute__((address_space(1))) void*)(B + (rowB0 + r1) * K + k0 + cc),
        (__attribute__((address_space(3))) void*)(Bs + (sgrp + 1) * 512), 16, 0, 0);
    __syncthreads();
    bf16x8 af[4], bf[4];
    #pragma unroll
    for (int m = 0; m < 4; ++m)
      af[m] = *reinterpret_cast<const bf16x8*>(&As[(wm + m * 16 + lr) * 32 + koff]);
    #pragma unroll
    for (int n = 0; n < 4; ++n)
      bf[n] = *reinterpret_cast<const bf16x8*>(&Bs[(wn + n * 16 + lr) * 32 + koff]);
    #pragma unroll
    for (int m = 0; m < 4; ++m)
      #pragma unroll
      for (int n = 0; n < 4; ++n)
        acc[m][n] = __builtin_amdgcn_mfma_f32_16x16x32_bf16(af[m], bf[n], acc[m][n], 0, 0, 0);
  }

  const int rg = (lane >> 4) * 4;
  #pragma unroll
  for (int m = 0; m < 4; ++m) {
    #pragma unroll
    for (int n = 0; n < 4; ++n) {
      #pragma unroll
      for (int r = 0; r < 4; ++r) {
        int row = (int)rowA0 + wm + m * 16 + rg + r;
        int col = (int)rowB0 + wn + n * 16 + lr;
        float v = acc[m][n][r];
        if (BIAS == 2) v += bias[row];
        ((unsigned short*)Cp + (size_t)z * sC)[(size_t)row * ldc + col] = f2bf(v);
      }
    }
  }
}

// ---------------- pipelined NT GEMM with SB-pinned chunk pipeline -----------
// A-tile MT=MF*32 x BK=64; B-tile 256 x 64. 8 waves (2M x 4N), acc[MF][4].
// Per K-tile, 5 sched_barrier(0)-pinned regions (reads one chunk ahead of
// their consuming MFMAs -> LDS pipe overlaps matrix pipe within each wave):
//  [R af-lo, R bfA] | [R bfB, M loxA] | [R af-hi, M loxB] | [M hixA] | [M hixB]
// Tile boundary (as R6): BAR; STAGE(k+2); vmcnt(LOADS); BAR.
// Swizzle: 16B slot p of row r holds global slot p ^ (r&7) (both sides).
// MODE 0: store bf16 exp(scale*acc + bias[z*sBias + col])   (E with T-col).
// MODE 1: store f32 acc/colsum(B) + bias[row] + resid       (final output).
#define BAR() do { asm volatile("" ::: "memory"); __builtin_amdgcn_s_barrier(); \
                   asm volatile("" ::: "memory"); } while (0)
#define SB() __builtin_amdgcn_sched_barrier(0)

template<int MF, int MODE, int GX, int GY>
__global__ __launch_bounds__(512, 2) void gemm_p(
    const unsigned short* __restrict__ A, long sA,
    const unsigned short* __restrict__ B, long sB,
    void* __restrict__ Cp, long sC,
    int K, int lda, int ldb, int ldc, float scale,
    const float* __restrict__ bias, long sBias,
    const float* __restrict__ resid, long sR) {
  constexpr int MT   = MF * 32;
  constexpr int ABUF = MT * 64;
  constexpr int MB2  = MF / 2;
  __shared__ unsigned short lds[2 * ABUF + 32768];
  unsigned short* Ab = lds;
  unsigned short* Bb = lds + 2 * ABUF;

  int flat = blockIdx.x + GX * (blockIdx.y + GY * blockIdx.z);
  const int nwg = GX * GY * gridDim.z;
  flat = (flat & 7) * (nwg >> 3) + (flat >> 3);
  const int bx = flat & (GX - 1);
  const int by = (flat / GX) & (GY - 1);
  const int z  = flat / (GX * GY);

  const unsigned short* Ag = A + (size_t)z * sA + (size_t)bx * MT * lda;
  const unsigned short* Bg = B + (size_t)z * sB + (size_t)by * 256 * ldb;
  const int tid = threadIdx.x;
  const int wid = tid >> 6, lane = tid & 63;
  const int wr = wid >> 2, wc = wid & 3;
  const int lr = lane & 15, q = lane >> 4;
  const int ssl = (lane & 7) ^ ((lane >> 3) & 7);
  const int sw = lr & 7;
  const int s0 = (q ^ sw) * 8;
  const int s1 = s0 ^ 32;
  const unsigned short* aR = Ab + (wr * (MT / 2) + lr) * 64;
  const unsigned short* bR = Bb + (wc * 64 + lr) * 64;

  auto STAGE_A = [&](int tt) {
    const int bb = tt & 1, k0 = tt << 6;
    #pragma unroll
    for (int h = 0; h < MT / 128; ++h)
      #pragma unroll
      for (int j = 0; j < 2; ++j) {
        const int row = h * 128 + (wid * 2 + j) * 8 + (lane >> 3);
        __builtin_amdgcn_global_load_lds(
            (const __attribute__((address_space(1))) void*)(
                Ag + (size_t)row * lda + k0 + ssl * 8),
            (__attribute__((address_space(3))) void*)(
                Ab + bb * ABUF + h * 8192 + (wid * 2 + j) * 512),
            16, 0, 0);
      }
  };
  auto STAGE_B = [&](int tt) {
    const int bb = tt & 1, k0 = tt << 6;
    #pragma unroll
    for (int h = 0; h < 2; ++h)
      #pragma unroll
      for (int j = 0; j < 2; ++j) {
        const int row = h * 128 + (wid * 2 + j) * 8 + (lane >> 3);
        __builtin_amdgcn_global_load_lds(
            (const __attribute__((address_space(1))) void*)(
                Bg + (size_t)row * ldb + k0 + ssl * 8),
            (__attribute__((address_space(3))) void*)(
                Bb + bb * 16384 + h * 8192 + (wid * 2 + j) * 512),
            16, 0, 0);
      }
  };

  f32x4 acc[MF][4] = {};
  f32x4 rsum[4] = {};
  bf16x8 af[MB2][2], ah[MB2][2], bfA[2][2], bfB[2][2];
  bf16x8 onesf;
  #pragma unroll
  for (int i = 0; i < 8; ++i) onesf[i] = (__bf16)1.0f;

  auto READ_A = [&](bf16x8 (&R)[MB2][2], int aoff, int MB) {
    #pragma unroll
    for (int mi = 0; mi < MB2; ++mi) {
      R[mi][0] = *reinterpret_cast<const bf16x8*>(aR + aoff + (MB + mi) * 1024 + s0);
      R[mi][1] = *reinterpret_cast<const bf16x8*>(aR + aoff + (MB + mi) * 1024 + s1);
    }
  };
  auto READ_B = [&](int boff, bf16x8 (&R)[2][2], int NB) {
    #pragma unroll
    for (int n = 0; n < 2; ++n) {
      R[n][0] = *reinterpret_cast<const bf16x8*>(bR + boff + (NB + n) * 1024 + s0);
      R[n][1] = *reinterpret_cast<const bf16x8*>(bR + boff + (NB + n) * 1024 + s1);
    }
  };
  auto MFQ = [&](bf16x8 (&AR)[MB2][2], int MB, bf16x8 (&R)[2][2], int NB) {
    #pragma unroll
    for (int kk = 0; kk < 2; ++kk)
      #pragma unroll
      for (int mi = 0; mi < MB2; ++mi)
        #pragma unroll
        for (int n = 0; n < 2; ++n)
          acc[MB + mi][NB + n] = __builtin_amdgcn_mfma_f32_16x16x32_bf16(
              AR[mi][kk], R[n][kk], acc[MB + mi][NB + n], 0, 0, 0);
  };
  auto RSUMQ = [&](bf16x8 (&R)[2][2], int NB) {
    if (MODE == 1) {
      #pragma unroll
      for (int kk = 0; kk < 2; ++kk)
        #pragma unroll
        for (int n = 0; n < 2; ++n)
          rsum[NB + n] = __builtin_amdgcn_mfma_f32_16x16x32_bf16(
              onesf, R[n][kk], rsum[NB + n], 0, 0, 0);
    }
  };
  auto WAITV = [&]() {
    if (MF == 8) asm volatile("s_waitcnt vmcnt(8)" ::: "memory");
    else         asm volatile("s_waitcnt vmcnt(6)" ::: "memory");
  };
  auto BODY = [&](int k) {
    const int aoff = (k & 1) * ABUF;
    const int boff = (k & 1) * 16384;
    READ_A(af, aoff, 0);
    READ_B(boff, bfA, 0);
    SB();
    READ_B(boff, bfB, 2);
    MFQ(af, 0, bfA, 0); RSUMQ(bfA, 0);
    SB();
    READ_A(ah, aoff, MB2);
    MFQ(af, 0, bfB, 2); RSUMQ(bfB, 2);
    SB();
    MFQ(ah, MB2, bfA, 0);
    SB();
    MFQ(ah, MB2, bfB, 2);
  };

  const int NT = K >> 6;
  STAGE_B(0); STAGE_A(0); STAGE_B(1); STAGE_A(1);
  WAITV();
  BAR();

  for (int k = 0; k < NT; ++k) {
    BODY(k);
    if (k + 1 < NT) {
      BAR();  // all waves done reading parity k&1
      if (k + 2 < NT) {
        STAGE_B(k + 2); STAGE_A(k + 2);
        WAITV();
      } else {
        asm volatile("s_waitcnt vmcnt(0)" ::: "memory");
      }
      BAR();  // everyone's tile-(k+1) loads landed
    }
  }

  const int rg = q * 4;
  if (MODE == 0) {
    unsigned short* Co = (unsigned short*)Cp + (size_t)z * sC;
    const float* Tz = bias + (size_t)z * sBias;
    #pragma unroll
    for (int m = 0; m < MF; ++m)
      #pragma unroll
      for (int n = 0; n < 4; ++n) {
        const int col = by * 256 + wc * 64 + n * 16 + lr;
        const float tb = Tz[col];
        #pragma unroll
        for (int r = 0; r < 4; ++r) {
          int row = bx * MT + wr * (MT / 2) + m * 16 + rg + r;
          Co[(size_t)row * ldc + col] = f2bf(__expf(acc[m][n][r] * scale + tb));
        }
      }
  } else {
    float* Co = (float*)Cp + (size_t)z * sC;
    const float* Rs = resid + (size_t)z * sR;
    #pragma unroll
    for (int m = 0; m < MF; ++m)
      #pragma unroll
      for (int n = 0; n < 4; ++n)
        #pragma unroll
        for (int r = 0; r < 4; ++r) {
          int row = bx * MT + wr * (MT / 2) + m * 16 + rg + r;
          int col = by * 256 + wc * 64 + n * 16 + lr;
          size_t idx = (size_t)row * ldc + col;
          Co[idx] = acc[m][n][r] / rsum[n][r] + bias[row] + Rs[idx];
        }
  }
}

extern "C" void kernel_launch(void* const* d_in, const int* in_sizes, int n_in,
                              void* d_out, int out_size, void* d_ws, size_t ws_size,
                              hipStream_t stream) {
  const float* x  = (const float*)d_in[0];
  const float* wq = (const float*)d_in[1];
  const float* bq = (const float*)d_in[2];
  const float* wk = (const float*)d_in[3];
  const float* bv = (const float*)d_in[6];
  const float* wv = (const float*)d_in[5];
  const float* wp = (const float*)d_in[7];
  const float* bp = (const float*)d_in[8];
  float* out = (float*)d_out;
  char* ws = (char*)d_ws;
  const size_t MB = 1024 * 1024;
  const long W2 = (long)C_DIM * C_DIM;  // 262144 elems
  unsigned short* Wqt = (unsigned short*)(ws + 0);                // [c,o] bf16
  unsigned short* Wpb = (unsigned short*)(ws + 512 * 1024);       // [o,c] bf16
  unsigned short* Wkt = (unsigned short*)(ws + 1 * MB);           // [c,o]
  unsigned short* Wvt = (unsigned short*)(ws + MB + 512 * 1024);  // [c,o]
  unsigned short* Mm  = (unsigned short*)(ws + 2 * MB);           // M = Wq^T Wk
  unsigned short* Wpv = (unsigned short*)(ws + 2 * MB + 512 * 1024);
  float* u   = (float*)(ws + 3 * MB);            // Wk^T bq [512]
  float* bvp = (float*)(ws + 3 * MB + 8 * 1024); // Wp bv   [512]
  float* Tf  = (float*)(ws + 4 * MB);            // T [B*N] f32
  unsigned short* Xt  = (unsigned short*)(ws + 5 * MB);   // [B,N,C]
  unsigned short* Z   = (unsigned short*)(ws + 21 * MB);  // [B,N,C]  Xt.M^T
  unsigned short* PVt = (unsigned short*)(ws + 37 * MB);  // [B,C,N]  Wpv.Xt^T
  unsigned short* P   = (unsigned short*)(ws + 53 * MB);  // E [N,N] x (1|4)
  const long NCe = (long)N_DIM * C_DIM;
  const long NNe = (long)N_DIM * N_DIM;
  const long PVe = (long)C_DIM * N_DIM;
  const float rs = 0.044194173824159216f;  // 1/sqrt(512)
  const bool big = ws_size >= 53 * MB + 4 * (size_t)N_DIM * N_DIM * 2;

  cvtT_weights<<<dim3(16, 16, 4), dim3(32, 8), 0, stream>>>(
      wq, wk, wv, wp, Wqt, Wkt, Wvt, Wpb);
  vec_prep<<<dim3(2), dim3(512), 0, stream>>>(wk, bq, wp, bv, u, bvp);
  // z=0: M = NT(Wqt, Wkt) ; z=1: Wpv = NT(Wpb, Wvt)
  gemm_nt<0><<<dim3(4, 4, 2), 256, 0, stream>>>(
      Wqt, W2, Wkt, W2, Mm, W2, C_DIM, C_DIM, nullptr);
  transpose_x<<<dim3(N_DIM / 32, C_DIM / 32, B_DIM), dim3(32, 8), 0, stream>>>(x, Xt);
  rowdot_T<<<dim3(B_DIM * N_DIM / 4), 256, 0, stream>>>(Xt, u, Tf);
  // Z[j,a] = sum_b Xt[j,b] M[a,b]
  gemm_nt<0><<<dim3(32, 4, 4), 256, 0, stream>>>(
      Xt, NCe, Mm, 0, Z, NCe, C_DIM, C_DIM, nullptr);
  // PVt[o,j] = sum_c Wpv[o,c] Xt[j,c] + bvp[o]
  gemm_nt<2><<<dim3(4, 32, 4), 256, 0, stream>>>(
      Wpv, 0, Xt, NCe, PVt, PVe, C_DIM, N_DIM, bvp);

  if (big) {
    // E = exp(rs * Xt.Z^T + T[col])
    gemm_p<8, 0, 16, 16><<<dim3(16, 16, 4), 512, 0, stream>>>(
        Xt, NCe, Z, NCe, P, NNe, C_DIM, C_DIM, C_DIM, N_DIM, rs,
        Tf, N_DIM, nullptr, 0);
    // out[o,n] = sum_j PVt[o,j] E[n,j] / colsum_j E[n,j] + bp[o] + x[o,n]
    gemm_p<4, 1, 4, 16><<<dim3(4, 16, 4), 512, 0, stream>>>(
        PVt, PVe, P, NNe, out, NCe, N_DIM, N_DIM, N_DIM, N_DIM, 1.0f,
        bp, 0, x, NCe);
  } else {
    for (int b = 0; b < B_DIM; ++b) {
      gemm_p<8, 0, 16, 16><<<dim3(16, 16, 1), 512, 0, stream>>>(
          Xt + (size_t)b * NCe, 0, Z + (size_t)b * NCe, 0, P, 0,
          C_DIM, C_DIM, C_DIM, N_DIM, rs, Tf + (size_t)b * N_DIM, 0, nullptr, 0);
      gemm_p<4, 1, 4, 16><<<dim3(4, 16, 1), 512, 0, stream>>>(
          PVt + (size_t)b * PVe, 0, P, 0, (void*)(out + (size_t)b * NCe), 0,
          N_DIM, N_DIM, N_DIM, N_DIM, 1.0f, bp, 0, x + (size_t)b * NCe, 0);
    }
  }
}

// Round 8
// 260.029 us; speedup vs baseline: 1.0179x; 1.0179x over previous
//
#include <hip/hip_runtime.h>
#include <hip/hip_bf16.h>
#include <stdint.h>

// B=4, C=512, H=W=64 -> N=4096. Channel-first x [B,C,N].
#define C_DIM 512
#define N_DIM 4096
#define B_DIM 4

typedef __bf16 bf16x8 __attribute__((ext_vector_type(8)));
typedef float f32x4 __attribute__((ext_vector_type(4)));
#define AS1 __attribute__((address_space(1)))
#define AS3 __attribute__((address_space(3)))

static __device__ __forceinline__ unsigned short f2bf(float x) {
  unsigned u = __float_as_uint(x);
  unsigned r = (u + 0x7fffu + ((u >> 16) & 1u)) >> 16;
  return (unsigned short)r;
}

// convert weights to bf16; transpose wq,wk,wv (z=0,1,2), straight-copy wp (z=3)
__global__ __launch_bounds__(256) void cvtT_weights(
    const float* __restrict__ wq, const float* __restrict__ wk,
    const float* __restrict__ wv, const float* __restrict__ wp,
    unsigned short* __restrict__ oq, unsigned short* __restrict__ ok,
    unsigned short* __restrict__ ov, unsigned short* __restrict__ op) {
  __shared__ float t[32][33];
  const int zz = blockIdx.z;
  const float* w = zz == 0 ? wq : zz == 1 ? wk : zz == 2 ? wv : wp;
  unsigned short* o = zz == 0 ? oq : zz == 1 ? ok : zz == 2 ? ov : op;
  const int r0 = blockIdx.y * 32, c0 = blockIdx.x * 32;
  const int tx = threadIdx.x, ty = threadIdx.y;
  if (zz < 3) {
    #pragma unroll
    for (int i = ty; i < 32; i += 8) t[i][tx] = w[(r0 + i) * C_DIM + c0 + tx];
    __syncthreads();
    #pragma unroll
    for (int i = ty; i < 32; i += 8)
      o[(size_t)(c0 + i) * C_DIM + r0 + tx] = f2bf(t[tx][i]);
  } else {
    #pragma unroll
    for (int i = ty; i < 32; i += 8)
      o[(size_t)(r0 + i) * C_DIM + c0 + tx] = f2bf(w[(r0 + i) * C_DIM + c0 + tx]);
  }
}

// u[c] = sum_o wk[o,c]*bq[o]  (block 0);  bvp[o] = sum_m wp[o,m]*bv[m] (block 1)
__global__ __launch_bounds__(512) void vec_prep(
    const float* __restrict__ wk, const float* __restrict__ bq,
    const float* __restrict__ wp, const float* __restrict__ bv,
    float* __restrict__ u, float* __restrict__ bvp) {
  const int t = threadIdx.x;
  if (blockIdx.x == 0) {
    float s = 0.f;
    #pragma unroll 8
    for (int o = 0; o < C_DIM; ++o) s += wk[(size_t)o * C_DIM + t] * bq[o];
    u[t] = s;
  } else {
    float s = 0.f;
    #pragma unroll 8
    for (int m = 0; m < C_DIM; ++m) s += wp[(size_t)t * C_DIM + m] * bv[m];
    bvp[t] = s;
  }
}

// x [B,C,N] f32 -> Xt [B,N,C] bf16
__global__ __launch_bounds__(256) void transpose_x(
    const float* __restrict__ x, unsigned short* __restrict__ Xt) {
  __shared__ float t[32][33];
  const int b = blockIdx.z;
  const float* xb = x + (size_t)b * C_DIM * N_DIM;
  unsigned short* xtb = Xt + (size_t)b * N_DIM * C_DIM;
  const int n0 = blockIdx.x * 32, c0 = blockIdx.y * 32;
  const int tx = threadIdx.x, ty = threadIdx.y;
  #pragma unroll
  for (int i = ty; i < 32; i += 8)
    t[i][tx] = xb[(size_t)(c0 + i) * N_DIM + n0 + tx];
  __syncthreads();
  #pragma unroll
  for (int i = ty; i < 32; i += 8)
    xtb[(size_t)(n0 + i) * C_DIM + c0 + tx] = f2bf(t[tx][i]);
}

// T[row] = rs * sum_c Xt[row,c]*u[c]   (wave per row, 4 rows/block)
__global__ __launch_bounds__(256) void rowdot_T(
    const unsigned short* __restrict__ Xt, const float* __restrict__ u,
    float* __restrict__ T) {
  const int row = blockIdx.x * 4 + (threadIdx.x >> 6);
  const int lane = threadIdx.x & 63;
  uint4 v = *reinterpret_cast<const uint4*>(Xt + (size_t)row * C_DIM + lane * 8);
  unsigned ua[4] = {v.x, v.y, v.z, v.w};
  const float* up = u + lane * 8;
  float s = 0.f;
  #pragma unroll
  for (int i = 0; i < 4; ++i) {
    s += __uint_as_float(ua[i] << 16) * up[2 * i];
    s += __uint_as_float(ua[i] & 0xffff0000u) * up[2 * i + 1];
  }
  #pragma unroll
  for (int off = 32; off >= 1; off >>= 1) s += __shfl_xor(s, off);
  if (lane == 0) T[row] = 0.044194173824159216f * s;
}

// ---------------- 128^2-tile 2-phase NT GEMM (small/mid GEMMs) -------------
// C[i,j] = sum_k A[i,k]B[j,k]; BIAS: 0 none, 2 +bias[row]. bf16 out.
template<int BIAS>
__global__ __launch_bounds__(256, 2) void gemm_nt(
    const unsigned short* __restrict__ A, long sA,
    const unsigned short* __restrict__ B, long sB,
    unsigned short* __restrict__ Cp, long sC,
    int K, int ldc, const float* __restrict__ bias) {
  const int z = blockIdx.z;
  A += (size_t)z * sA;
  B += (size_t)z * sB;
  const int tid = threadIdx.x;
  const int wid = tid >> 6, lane = tid & 63;
  __shared__ unsigned short As[128 * 32];
  __shared__ unsigned short Bs[128 * 32];
  const int wm = (wid >> 1) * 64, wn = (wid & 1) * 64;
  f32x4 acc[4][4] = {};
  const size_t rowA0 = (size_t)blockIdx.x * 128;
  const size_t rowB0 = (size_t)blockIdx.y * 128;
  const int sgrp = wid * 2;
  const int r0 = (sgrp * 64 + lane) >> 2;
  const int r1 = ((sgrp + 1) * 64 + lane) >> 2;
  const int cc = ((lane & 3) ^ ((lane >> 3) & 3)) * 8;
  const int lr = lane & 15;
  const int koff = (((lane >> 4) ^ ((lr >> 1) & 3))) * 8;

  for (int k0 = 0; k0 < K; k0 += 32) {
    __syncthreads();
    __builtin_amdgcn_global_load_lds(
        (const AS1 void*)(A + (rowA0 + r0) * K + k0 + cc),
        (AS3 void*)(As + sgrp * 512), 16, 0, 0);
    __builtin_amdgcn_global_load_lds(
        (const AS1 void*)(A + (rowA0 + r1) * K + k0 + cc),
        (AS3 void*)(As + (sgrp + 1) * 512), 16, 0, 0);
    __builtin_amdgcn_global_load_lds(
        (const AS1 void*)(B + (rowB0 + r0) * K + k0 + cc),
        (AS3 void*)(Bs + sgrp * 512), 16, 0, 0);
    __builtin_amdgcn_global_load_lds(
        (const AS1 void*)(B + (rowB0 + r1) * K + k0 + cc),
        (AS3 void*)(Bs + (sgrp + 1) * 512), 16, 0, 0);
    __syncthreads();
    bf16x8 af[4], bf[4];
    #pragma unroll
    for (int m = 0; m < 4; ++m)
      af[m] = *reinterpret_cast<const bf16x8*>(&As[(wm + m * 16 + lr) * 32 + koff]);
    #pragma unroll
    for (int n = 0; n < 4; ++n)
      bf[n] = *reinterpret_cast<const bf16x8*>(&Bs[(wn + n * 16 + lr) * 32 + koff]);
    #pragma unroll
    for (int m = 0; m < 4; ++m)
      #pragma unroll
      for (int n = 0; n < 4; ++n)
        acc[m][n] = __builtin_amdgcn_mfma_f32_16x16x32_bf16(af[m], bf[n], acc[m][n], 0, 0, 0);
  }

  const int rg = (lane >> 4) * 4;
  #pragma unroll
  for (int m = 0; m < 4; ++m) {
    #pragma unroll
    for (int n = 0; n < 4; ++n) {
      #pragma unroll
      for (int r = 0; r < 4; ++r) {
        int row = (int)rowA0 + wm + m * 16 + rg + r;
        int col = (int)rowB0 + wn + n * 16 + lr;
        float v = acc[m][n][r];
        if (BIAS == 2) v += bias[row];
        ((unsigned short*)Cp + (size_t)z * sC)[(size_t)row * ldc + col] = f2bf(v);
      }
    }
  }
}

// ---------------- pipelined NT GEMM, loop-invariant addressing --------------
// A-tile MT=MF*32 x BK=64; B-tile 256 x 64. 8 waves (2M x 4N), acc[MF][4].
// K-loop unrolled by 2 => buffer parity is COMPILE-TIME:
//   - all ds_reads are lane-constant pointer + immediate offset (zero VALU),
//   - staging = uniform SGPR base + precomputed per-lane int voffset + tt*64.
// Sync per tile (proven race-free, R6): BODY (free-scheduled reads+MFMA on
// parity P; reads hit data staged 2 tiles ago) ; BAR ; STAGE(P, k+2) ;
// vmcnt(LOADS) (tile k+1 landed, k+2 in flight) ; BAR.
// Swizzle: 16B slot p of row r holds global slot p ^ (r&7) (both sides).
// MODE 0: store bf16 exp(scale*acc + bias[z*sBias + col])   (E with T-col).
// MODE 1: store f32 acc/colsum(B) + bias[row] + resid       (final output).
#define BAR() do { asm volatile("" ::: "memory"); __builtin_amdgcn_s_barrier(); \
                   asm volatile("" ::: "memory"); } while (0)

template<int MF, int MODE, int GX, int GY>
__global__ __launch_bounds__(512, 2) void gemm_p(
    const unsigned short* __restrict__ A, long sA,
    const unsigned short* __restrict__ B, long sB,
    void* __restrict__ Cp, long sC,
    int K, int lda, int ldb, int ldc, float scale,
    const float* __restrict__ bias, long sBias,
    const float* __restrict__ resid, long sR) {
  constexpr int MT     = MF * 32;
  constexpr int ABUF   = MT * 64;       // shorts per A parity buffer
  constexpr int MB2    = MF / 2;
  constexpr int ALOADS = (MT / 128) * 2;
  constexpr int LOADS  = ALOADS + 4;    // per-wave gloads per tile
  __shared__ unsigned short lds[2 * ABUF + 32768];
  unsigned short* Ab = lds;
  unsigned short* Bb = lds + 2 * ABUF;

  // XCD-aware bijective block swizzle (nwg % 8 == 0 at all call sites)
  int flat = blockIdx.x + GX * (blockIdx.y + GY * blockIdx.z);
  const int nwg = GX * GY * gridDim.z;
  flat = (flat & 7) * (nwg >> 3) + (flat >> 3);
  const int bx = flat & (GX - 1);
  const int by = (flat / GX) & (GY - 1);
  const int z  = flat / (GX * GY);

  const unsigned short* Ag = A + (size_t)z * sA + (size_t)bx * MT * lda;
  const unsigned short* Bg = B + (size_t)z * sB + (size_t)by * 256 * ldb;
  const int tid = threadIdx.x;
  const int wid = tid >> 6, lane = tid & 63;
  const int wr = wid >> 2, wc = wid & 3;
  const int lr = lane & 15, q = lane >> 4;
  const int ssl = (lane & 7) ^ ((lane >> 3) & 7);
  const int sw = lr & 7;
  const int s0 = (q ^ sw) * 8;
  const int s1 = s0 ^ 32;

  // lane-constant LDS read pointers; all loop reads are ptr[imm]
  const unsigned short* a0 = Ab + (wr * (MT / 2) + lr) * 64 + s0;
  const unsigned short* a1 = Ab + (wr * (MT / 2) + lr) * 64 + s1;
  const unsigned short* b0 = Bb + (wc * 64 + lr) * 64 + s0;
  const unsigned short* b1 = Bb + (wc * 64 + lr) * 64 + s1;

  // per-lane staging voffsets (elements), loop adds tt*64 only
  int agv[ALOADS], bgv[4];
  #pragma unroll
  for (int i = 0; i < ALOADS; ++i)
    agv[i] = ((i >> 1) * 128 + (wid * 2 + (i & 1)) * 8 + (lane >> 3)) * lda + ssl * 8;
  #pragma unroll
  for (int i = 0; i < 4; ++i)
    bgv[i] = ((i >> 1) * 128 + (wid * 2 + (i & 1)) * 8 + (lane >> 3)) * ldb + ssl * 8;

  auto STAGE = [&](int P, int tt) {  // P literal at every call site
    const int t64 = tt << 6;
    #pragma unroll
    for (int i = 0; i < ALOADS; ++i)
      __builtin_amdgcn_global_load_lds(
          (const AS1 void*)(Ag + agv[i] + t64),
          (AS3 void*)(Ab + P * ABUF + (i >> 1) * 8192 + (wid * 2 + (i & 1)) * 512),
          16, 0, 0);
    #pragma unroll
    for (int i = 0; i < 4; ++i)
      __builtin_amdgcn_global_load_lds(
          (const AS1 void*)(Bg + bgv[i] + t64),
          (AS3 void*)(Bb + P * 16384 + (i >> 1) * 8192 + (wid * 2 + (i & 1)) * 512),
          16, 0, 0);
  };

  f32x4 acc[MF][4] = {};
  f32x4 rsum[4] = {};
  bf16x8 onesf;
  #pragma unroll
  for (int i = 0; i < 8; ++i) onesf[i] = (__bf16)1.0f;

  auto BODY = [&](int P) {  // P literal at every call site
    const int ao = P * ABUF;
    const int bo = P * 16384;
    bf16x8 af[MB2][2], ah[MB2][2], bA[2][2], bB[2][2];
    #pragma unroll
    for (int mi = 0; mi < MB2; ++mi) {
      af[mi][0] = *reinterpret_cast<const bf16x8*>(a0 + ao + mi * 1024);
      af[mi][1] = *reinterpret_cast<const bf16x8*>(a1 + ao + mi * 1024);
    }
    #pragma unroll
    for (int n = 0; n < 2; ++n) {
      bA[n][0] = *reinterpret_cast<const bf16x8*>(b0 + bo + n * 1024);
      bA[n][1] = *reinterpret_cast<const bf16x8*>(b1 + bo + n * 1024);
      bB[n][0] = *reinterpret_cast<const bf16x8*>(b0 + bo + (2 + n) * 1024);
      bB[n][1] = *reinterpret_cast<const bf16x8*>(b1 + bo + (2 + n) * 1024);
    }
    #pragma unroll
    for (int mi = 0; mi < MB2; ++mi) {
      ah[mi][0] = *reinterpret_cast<const bf16x8*>(a0 + ao + (MB2 + mi) * 1024);
      ah[mi][1] = *reinterpret_cast<const bf16x8*>(a1 + ao + (MB2 + mi) * 1024);
    }
    #pragma unroll
    for (int kk = 0; kk < 2; ++kk)
      #pragma unroll
      for (int mi = 0; mi < MB2; ++mi)
        #pragma unroll
        for (int n = 0; n < 2; ++n) {
          acc[mi][n]     = __builtin_amdgcn_mfma_f32_16x16x32_bf16(af[mi][kk], bA[n][kk], acc[mi][n], 0, 0, 0);
          acc[mi][2 + n] = __builtin_amdgcn_mfma_f32_16x16x32_bf16(af[mi][kk], bB[n][kk], acc[mi][2 + n], 0, 0, 0);
        }
    if (MODE == 1) {
      #pragma unroll
      for (int kk = 0; kk < 2; ++kk)
        #pragma unroll
        for (int n = 0; n < 2; ++n) {
          rsum[n]     = __builtin_amdgcn_mfma_f32_16x16x32_bf16(onesf, bA[n][kk], rsum[n], 0, 0, 0);
          rsum[2 + n] = __builtin_amdgcn_mfma_f32_16x16x32_bf16(onesf, bB[n][kk], rsum[2 + n], 0, 0, 0);
        }
    }
    #pragma unroll
    for (int kk = 0; kk < 2; ++kk)
      #pragma unroll
      for (int mi = 0; mi < MB2; ++mi)
        #pragma unroll
        for (int n = 0; n < 2; ++n) {
          acc[MB2 + mi][n]     = __builtin_amdgcn_mfma_f32_16x16x32_bf16(ah[mi][kk], bA[n][kk], acc[MB2 + mi][n], 0, 0, 0);
          acc[MB2 + mi][2 + n] = __builtin_amdgcn_mfma_f32_16x16x32_bf16(ah[mi][kk], bB[n][kk], acc[MB2 + mi][2 + n], 0, 0, 0);
        }
  };

  auto WAITV = [&]() {
    if (LOADS == 8) asm volatile("s_waitcnt vmcnt(8)" ::: "memory");
    else            asm volatile("s_waitcnt vmcnt(6)" ::: "memory");
  };

  const int NT = K >> 6;
  STAGE(0, 0); STAGE(1, 1);
  WAITV();
  BAR();

  for (int k = 0; k < NT; k += 2) {
    BODY(0);
    BAR();
    if (k + 2 < NT) { STAGE(0, k + 2); WAITV(); }
    else { asm volatile("s_waitcnt vmcnt(0)" ::: "memory"); }
    BAR();
    BODY(1);
    if (k + 2 < NT) {
      BAR();
      if (k + 3 < NT) { STAGE(1, k + 3); WAITV(); }
      else { asm volatile("s_waitcnt vmcnt(0)" ::: "memory"); }
      BAR();
    }
  }

  const int rg = q * 4;
  if (MODE == 0) {
    unsigned short* Co = (unsigned short*)Cp + (size_t)z * sC;
    const float* Tz = bias + (size_t)z * sBias;
    #pragma unroll
    for (int m = 0; m < MF; ++m)
      #pragma unroll
      for (int n = 0; n < 4; ++n) {
        const int col = by * 256 + wc * 64 + n * 16 + lr;
        const float tb = Tz[col];
        #pragma unroll
        for (int r = 0; r < 4; ++r) {
          int row = bx * MT + wr * (MT / 2) + m * 16 + rg + r;
          Co[(size_t)row * ldc + col] = f2bf(__expf(acc[m][n][r] * scale + tb));
        }
      }
  } else {
    float* Co = (float*)Cp + (size_t)z * sC;
    const float* Rs = resid + (size_t)z * sR;
    #pragma unroll
    for (int m = 0; m < MF; ++m)
      #pragma unroll
      for (int n = 0; n < 4; ++n)
        #pragma unroll
        for (int r = 0; r < 4; ++r) {
          int row = bx * MT + wr * (MT / 2) + m * 16 + rg + r;
          int col = by * 256 + wc * 64 + n * 16 + lr;
          size_t idx = (size_t)row * ldc + col;
          Co[idx] = acc[m][n][r] / rsum[n][r] + bias[row] + Rs[idx];
        }
  }
}

extern "C" void kernel_launch(void* const* d_in, const int* in_sizes, int n_in,
                              void* d_out, int out_size, void* d_ws, size_t ws_size,
                              hipStream_t stream) {
  const float* x  = (const float*)d_in[0];
  const float* wq = (const float*)d_in[1];
  const float* bq = (const float*)d_in[2];
  const float* wk = (const float*)d_in[3];
  const float* bv = (const float*)d_in[6];
  const float* wv = (const float*)d_in[5];
  const float* wp = (const float*)d_in[7];
  const float* bp = (const float*)d_in[8];
  float* out = (float*)d_out;
  char* ws = (char*)d_ws;
  const size_t MB = 1024 * 1024;
  const long W2 = (long)C_DIM * C_DIM;
  unsigned short* Wqt = (unsigned short*)(ws + 0);                // [c,o] bf16
  unsigned short* Wpb = (unsigned short*)(ws + 512 * 1024);       // [o,c] bf16
  unsigned short* Wkt = (unsigned short*)(ws + 1 * MB);           // [c,o]
  unsigned short* Wvt = (unsigned short*)(ws + MB + 512 * 1024);  // [c,o]
  unsigned short* Mm  = (unsigned short*)(ws + 2 * MB);           // M = Wq^T Wk
  unsigned short* Wpv = (unsigned short*)(ws + 2 * MB + 512 * 1024);
  float* u   = (float*)(ws + 3 * MB);            // Wk^T bq [512]
  float* bvp = (float*)(ws + 3 * MB + 8 * 1024); // Wp bv   [512]
  float* Tf  = (float*)(ws + 4 * MB);            // T [B*N] f32
  unsigned short* Xt  = (unsigned short*)(ws + 5 * MB);   // [B,N,C]
  unsigned short* Z   = (unsigned short*)(ws + 21 * MB);  // [B,N,C]  Xt.M^T
  unsigned short* PVt = (unsigned short*)(ws + 37 * MB);  // [B,C,N]  Wpv.Xt^T
  unsigned short* P   = (unsigned short*)(ws + 53 * MB);  // E [N,N] x (1|4)
  const long NCe = (long)N_DIM * C_DIM;
  const long NNe = (long)N_DIM * N_DIM;
  const long PVe = (long)C_DIM * N_DIM;
  const float rs = 0.044194173824159216f;  // 1/sqrt(512)
  const bool big = ws_size >= 53 * MB + 4 * (size_t)N_DIM * N_DIM * 2;

  cvtT_weights<<<dim3(16, 16, 4), dim3(32, 8), 0, stream>>>(
      wq, wk, wv, wp, Wqt, Wkt, Wvt, Wpb);
  vec_prep<<<dim3(2), dim3(512), 0, stream>>>(wk, bq, wp, bv, u, bvp);
  gemm_nt<0><<<dim3(4, 4, 2), 256, 0, stream>>>(
      Wqt, W2, Wkt, W2, Mm, W2, C_DIM, C_DIM, nullptr);
  transpose_x<<<dim3(N_DIM / 32, C_DIM / 32, B_DIM), dim3(32, 8), 0, stream>>>(x, Xt);
  rowdot_T<<<dim3(B_DIM * N_DIM / 4), 256, 0, stream>>>(Xt, u, Tf);
  gemm_nt<0><<<dim3(32, 4, 4), 256, 0, stream>>>(
      Xt, NCe, Mm, 0, Z, NCe, C_DIM, C_DIM, nullptr);
  gemm_nt<2><<<dim3(4, 32, 4), 256, 0, stream>>>(
      Wpv, 0, Xt, NCe, PVt, PVe, C_DIM, N_DIM, bvp);

  if (big) {
    gemm_p<8, 0, 16, 16><<<dim3(16, 16, 4), 512, 0, stream>>>(
        Xt, NCe, Z, NCe, P, NNe, C_DIM, C_DIM, C_DIM, N_DIM, rs,
        Tf, N_DIM, nullptr, 0);
    gemm_p<4, 1, 4, 16><<<dim3(4, 16, 4), 512, 0, stream>>>(
        PVt, PVe, P, NNe, out, NCe, N_DIM, N_DIM, N_DIM, N_DIM, 1.0f,
        bp, 0, x, NCe);
  } else {
    for (int b = 0; b < B_DIM; ++b) {
      gemm_p<8, 0, 16, 16><<<dim3(16, 16, 1), 512, 0, stream>>>(
          Xt + (size_t)b * NCe, 0, Z + (size_t)b * NCe, 0, P, 0,
          C_DIM, C_DIM, C_DIM, N_DIM, rs, Tf + (size_t)b * N_DIM, 0, nullptr, 0);
      gemm_p<4, 1, 4, 16><<<dim3(4, 16, 1), 512, 0, stream>>>(
          PVt + (size_t)b * PVe, 0, P, 0, (void*)(out + (size_t)b * NCe), 0,
          N_DIM, N_DIM, N_DIM, N_DIM, 1.0f, bp, 0, x + (size_t)b * NCe, 0);
    }
  }
}